// Round 1
// baseline (341.701 us; speedup 1.0000x reference)
//
#include <hip/hip_runtime.h>
#include <math.h>

// Problem constants (fixed shapes from reference):
// sources: [4][32][512][512] fp32, kernels: [12][3][3] fp32, out: [4][32][512][512] fp32
#define NCH  4
#define NIMG 32
#define HH   512
#define WW   512

// Tile: 64 wide x 16 high per block; halo of 1 on each side for 3x3 SAME conv.
#define TW   64
#define TH   16
#define HTW  (TW + 2)   // 66
#define HTH  (TH + 2)   // 18
#define HSZ  (HTH * HTW) // 1188

__global__ __launch_bounds__(256) void bleed_kernel(
    const float* __restrict__ src,   // [4][32][512][512]
    const float* __restrict__ ker,   // [12][3][3]
    float* __restrict__ out)         // [4][32][512][512]
{
    __shared__ float s_i [HTH][HTW];  // src_i halo tile
    __shared__ float e_i [HTH][HTW];  // cbrt(src_i)^2
    __shared__ float s_nb[HTH][HTW];  // neighbor tile (raw)
    __shared__ float t_nb[HTH][HTW];  // cbrt(s_nb) * e_i

    const int tid    = threadIdx.x;
    const int lx     = tid & 63;      // 0..63  (column within tile)
    const int ly0    = tid >> 6;      // 0..3   (row-group; each thread does 4 adjacent rows)
    const int tile_x = blockIdx.x * TW;
    const int tile_y = blockIdx.y * TH;
    const int ch     = blockIdx.z >> 5;   // /NIMG
    const int n      = blockIdx.z & 31;   // %NIMG

    const size_t plane = (size_t)HH * WW;
    const float* src_i = src + ((size_t)ch * NIMG + n) * plane;

    // ---- stage src_i halo tile (zero-padded) ----
    for (int idx = tid; idx < HSZ; idx += 256) {
        const int ly  = idx / HTW;
        const int lxx = idx - ly * HTW;
        const int gy  = tile_y - 1 + ly;
        const int gx  = tile_x - 1 + lxx;
        float v = 0.0f;
        if ((unsigned)gy < HH && (unsigned)gx < WW)
            v = src_i[(size_t)gy * WW + gx];
        (&s_i[0][0])[idx] = v;
    }
    __syncthreads();

    // ---- e_i = cbrt(s_i)^2  (== s_i^(2/3)) ----
    for (int idx = tid; idx < HSZ; idx += 256) {
        const float c = cbrtf((&s_i[0][0])[idx]);
        (&e_i[0][0])[idx] = c * c;
    }
    // (sync deferred: first neighbor loop syncs before anyone reads e_i)

    // ---- init accumulators with src_i center values ----
    const int r0 = ly0 * 4;           // first output row (tile-local) for this thread
    float acc[4];
    #pragma unroll
    for (int p = 0; p < 4; ++p)
        acc[p] = s_i[1 + r0 + p][1 + lx];

    // kidx base per channel: ch0->0, ch1->2, ch2->6, ch3->10
    int koff = (ch == 0) ? 0 : (ch == 1) ? 2 : (ch == 2) ? 6 : 10;

    // ---- neighbor loop: j = ch-1 then ch+1 (reference kidx order) ----
    #pragma unroll
    for (int s = 0; s < 2; ++s) {
        const int j = ch + (s == 0 ? -1 : 1);
        if (j < 0 || j >= NCH) continue;

        // 3x3 kernels (block-uniform -> scalar loads)
        float kc[9], ki[9];
        #pragma unroll
        for (int q = 0; q < 9; ++q) {
            kc[q] = ker[koff * 9 + q];
            ki[q] = ker[(koff + 1) * 9 + q];
        }
        koff += 2;

        __syncthreads();  // prev conv reads done; e_i writes visible

        // stage neighbor halo tile
        const float* src_j = src + ((size_t)j * NIMG + n) * plane;
        for (int idx = tid; idx < HSZ; idx += 256) {
            const int ly  = idx / HTW;
            const int lxx = idx - ly * HTW;
            const int gy  = tile_y - 1 + ly;
            const int gx  = tile_x - 1 + lxx;
            float v = 0.0f;
            if ((unsigned)gy < HH && (unsigned)gx < WW)
                v = src_j[(size_t)gy * WW + gx];
            (&s_nb[0][0])[idx] = v;
        }
        __syncthreads();

        // t_nb = cbrt(s_nb) * e_i   (the inter_term, one cbrtf per halo pixel)
        for (int idx = tid; idx < HSZ; idx += 256) {
            (&t_nb[0][0])[idx] = cbrtf((&s_nb[0][0])[idx]) * (&e_i[0][0])[idx];
        }
        __syncthreads();

        // ---- conv: load 6x3 windows once, compute 4 vertically-adjacent outputs ----
        float wn[6][3], wt[6][3];
        #pragma unroll
        for (int q = 0; q < 6; ++q) {
            #pragma unroll
            for (int c = 0; c < 3; ++c) {
                wn[q][c] = s_nb[r0 + q][lx + c];
                wt[q][c] = t_nb[r0 + q][lx + c];
            }
        }
        #pragma unroll
        for (int p = 0; p < 4; ++p) {
            float sum = 0.0f;
            #pragma unroll
            for (int dy = 0; dy < 3; ++dy) {
                #pragma unroll
                for (int dx = 0; dx < 3; ++dx) {
                    sum += wn[p + dy][dx] * kc[dy * 3 + dx]
                         + wt[p + dy][dx] * ki[dy * 3 + dx];
                }
            }
            acc[p] -= sum;
        }
    }

    // ---- write out (coalesced: full wave shares row, consecutive lx) ----
    const size_t obase = ((size_t)ch * NIMG + n) * plane;
    #pragma unroll
    for (int p = 0; p < 4; ++p) {
        const int gy = tile_y + r0 + p;
        const int gx = tile_x + lx;
        out[obase + (size_t)gy * WW + gx] = acc[p];
    }
}

extern "C" void kernel_launch(void* const* d_in, const int* in_sizes, int n_in,
                              void* d_out, int out_size, void* d_ws, size_t ws_size,
                              hipStream_t stream) {
    const float* src = (const float*)d_in[0];  // sources [4][32][512][512]
    const float* ker = (const float*)d_in[1];  // kernels [12][3][3]
    float* out = (float*)d_out;

    dim3 grid(WW / TW, HH / TH, NCH * NIMG);   // (8, 32, 128) = 32768 blocks
    dim3 block(256);
    bleed_kernel<<<grid, block, 0, stream>>>(src, ker, out);
}

// Round 2
// 325.539 us; speedup vs baseline: 1.0496x; 1.0496x over previous
//
#include <hip/hip_runtime.h>
#include <math.h>

// sources: [4][32][512][512] fp32, kernels: [12][3][3] fp32, out: same as sources
#define NCH  4
#define NIMG 32
#define HH   512
#define WW   512

// Tile 64 wide x 16 high; halo 1. All 4 channels handled by one block.
#define TW   64
#define TH   16
#define HTWU 66            // used halo width
#define HTW  68            // padded stride (272 B, 16B-aligned rows)
#define HTH  18
#define NPIX (HTH * HTWU)  // 1188 staged pixels per channel

#if __has_builtin(__builtin_amdgcn_exp2f)
#define EXP2(x) __builtin_amdgcn_exp2f(x)
#else
#define EXP2(x) exp2f(x)
#endif
#if __has_builtin(__builtin_amdgcn_logf)
#define LOG2(x) __builtin_amdgcn_logf(x)
#else
#define LOG2(x) __log2f(x)
#endif

// Load a 6-wide window row from a 16B-aligned LDS row pointer: b128 + b64.
__device__ __forceinline__ void load_row6(const float* __restrict__ row, float w[6]) {
    const float4 a = *(const float4*)row;
    const float2 b = *(const float2*)(row + 4);
    w[0] = a.x; w[1] = a.y; w[2] = a.z; w[3] = a.w; w[4] = b.x; w[5] = b.y;
}

// One directed pair (i <- j): t = exp2(0.5*l'_j + l'_i); acc_i -= conv(s_j,kc)+conv(t,ki)
// (we accumulate the bleed positively and subtract at the end)
__device__ __forceinline__ void conv_pair(
    const float wj[3][6], const float lj[3][6],
    const float (*sLi)[HTW],          // l' tile of channel i
    int ty, int tx4,
    const float* __restrict__ ker, int kcIdx, int kiIdx,
    float acc[4])
{
    float li[3][6], ti[3][6];
    #pragma unroll
    for (int r = 0; r < 3; ++r)
        load_row6(&sLi[ty + r][tx4], li[r]);
    #pragma unroll
    for (int r = 0; r < 3; ++r)
        #pragma unroll
        for (int q = 0; q < 6; ++q)
            ti[r][q] = EXP2(fmaf(lj[r][q], 0.5f, li[r][q]));

    float kc[9], ki9[9];
    #pragma unroll
    for (int q = 0; q < 9; ++q) {
        kc[q]  = ker[kcIdx * 9 + q];   // block-uniform -> s_load
        ki9[q] = ker[kiIdx * 9 + q];
    }
    #pragma unroll
    for (int q = 0; q < 4; ++q) {
        float s = 0.0f;
        #pragma unroll
        for (int dy = 0; dy < 3; ++dy)
            #pragma unroll
            for (int dx = 0; dx < 3; ++dx) {
                s = fmaf(wj[dy][q + dx], kc[dy * 3 + dx], s);
                s = fmaf(ti[dy][q + dx], ki9[dy * 3 + dx], s);
            }
        acc[q] += s;
    }
}

__global__ __launch_bounds__(256, 4) void bleed_kernel(
    const float* __restrict__ src,   // [4][32][512][512]
    const float* __restrict__ ker,   // [12][3][3]
    float* __restrict__ out)
{
    __shared__ __align__(16) float sS[NCH][HTH][HTW];  // raw sources
    __shared__ __align__(16) float sL[NCH][HTH][HTW];  // (2/3)*log2(source)

    const int tid    = threadIdx.x;
    const int tx     = tid & 15;      // col group: cols 4*tx .. 4*tx+3
    const int ty     = tid >> 4;      // row 0..15
    const int tx4    = tx * 4;
    const int tile_x = blockIdx.x * TW;
    const int tile_y = blockIdx.y * TH;
    const int n      = blockIdx.z;    // image index

    const size_t plane = (size_t)HH * WW;

    // ---- stage all 4 channels (raw + scaled log2), zero-padded halo ----
    for (int c = 0; c < NCH; ++c) {
        const float* sp = src + ((size_t)c * NIMG + n) * plane;
        for (int idx = tid; idx < NPIX; idx += 256) {
            const int ly  = idx / HTWU;
            const int lxx = idx - ly * HTWU;
            const int gy  = tile_y - 1 + ly;
            const int gx  = tile_x - 1 + lxx;
            float v = 0.0f;
            if ((unsigned)gy < HH && (unsigned)gx < WW)
                v = sp[(size_t)gy * WW + gx];
            sS[c][ly][lxx] = v;
            sL[c][ly][lxx] = 0.66666667f * LOG2(v);  // -inf for v==0 (correct)
        }
    }
    __syncthreads();   // the only barrier: everything after is read-only LDS

    float acc[NCH][4] = {{0.f}};

    // Pair list grouped by neighbor j (kidx order per reference):
    //  j=0: i=1 (kc=2, ki=3)
    //  j=1: i=0 (0,1), i=2 (6,7)
    //  j=2: i=1 (4,5), i=3 (10,11)
    //  j=3: i=2 (8,9)
    {
        float wj[3][6], lj[3][6];
        #pragma unroll
        for (int r = 0; r < 3; ++r) {
            load_row6(&sS[0][ty + r][tx4], wj[r]);
            load_row6(&sL[0][ty + r][tx4], lj[r]);
        }
        conv_pair(wj, lj, sL[1], ty, tx4, ker, 2, 3, acc[1]);
    }
    {
        float wj[3][6], lj[3][6];
        #pragma unroll
        for (int r = 0; r < 3; ++r) {
            load_row6(&sS[1][ty + r][tx4], wj[r]);
            load_row6(&sL[1][ty + r][tx4], lj[r]);
        }
        conv_pair(wj, lj, sL[0], ty, tx4, ker, 0, 1, acc[0]);
        conv_pair(wj, lj, sL[2], ty, tx4, ker, 6, 7, acc[2]);
    }
    {
        float wj[3][6], lj[3][6];
        #pragma unroll
        for (int r = 0; r < 3; ++r) {
            load_row6(&sS[2][ty + r][tx4], wj[r]);
            load_row6(&sL[2][ty + r][tx4], lj[r]);
        }
        conv_pair(wj, lj, sL[1], ty, tx4, ker, 4, 5, acc[1]);
        conv_pair(wj, lj, sL[3], ty, tx4, ker, 10, 11, acc[3]);
    }
    {
        float wj[3][6], lj[3][6];
        #pragma unroll
        for (int r = 0; r < 3; ++r) {
            load_row6(&sS[3][ty + r][tx4], wj[r]);
            load_row6(&sL[3][ty + r][tx4], lj[r]);
        }
        conv_pair(wj, lj, sL[2], ty, tx4, ker, 8, 9, acc[2]);
    }

    // ---- out = src_center - bleed ; dwordx4 stores ----
    const int gy  = tile_y + ty;
    const int gx0 = tile_x + tx4;
    #pragma unroll
    for (int c = 0; c < NCH; ++c) {
        float4 o;
        o.x = sS[c][ty + 1][tx4 + 1] - acc[c][0];
        o.y = sS[c][ty + 1][tx4 + 2] - acc[c][1];
        o.z = sS[c][ty + 1][tx4 + 3] - acc[c][2];
        o.w = sS[c][ty + 1][tx4 + 4] - acc[c][3];
        *(float4*)(out + ((size_t)c * NIMG + n) * plane + (size_t)gy * WW + gx0) = o;
    }
}

extern "C" void kernel_launch(void* const* d_in, const int* in_sizes, int n_in,
                              void* d_out, int out_size, void* d_ws, size_t ws_size,
                              hipStream_t stream) {
    const float* src = (const float*)d_in[0];
    const float* ker = (const float*)d_in[1];
    float* out = (float*)d_out;

    dim3 grid(WW / TW, HH / TH, NIMG);   // (8, 32, 32) = 8192 blocks
    dim3 block(256);
    bleed_kernel<<<grid, block, 0, stream>>>(src, ker, out);
}